// Round 10
// baseline (684.908 us; speedup 1.0000x reference)
//
#include <hip/hip_runtime.h>

typedef unsigned short u16;
typedef unsigned char  u8;
typedef unsigned int   u32;
typedef __attribute__((ext_vector_type(8)))  short short8;   // 8 bf16 (4 VGPRs)
typedef __attribute__((ext_vector_type(16))) float floatx16; // 32x32 MFMA C/D f32
typedef __attribute__((ext_vector_type(4)))  int   intx4;    // 16 i8 (4 VGPRs)
typedef __attribute__((ext_vector_type(16))) int   intx16;   // 32x32 i8 MFMA C/D
typedef __attribute__((ext_vector_type(8)))  u16   u16x8;
typedef __attribute__((ext_vector_type(4)))  u16   u16x4;

__device__ __forceinline__ u16 f2b(float f) {
    u32 u = __float_as_uint(f);
    u = (u + 0x7FFFu + ((u >> 16) & 1u)) >> 16;
    return (u16)u;
}
__device__ __forceinline__ float b2f(u16 h) {
    return __uint_as_float(((u32)h) << 16);
}
__device__ __forceinline__ int q8(float v, float inv) {
    return __float2int_rn(fminf(fmaxf(v * inv, -127.f), 127.f));
}

// ================= prep building blocks (256-thread granularity) ===========
__device__ __forceinline__ void pad_block(const float* __restrict__ Wsrc, int rows,
                                          u16* __restrict__ Wdst,
                                          const float* __restrict__ bsrc,
                                          float* __restrict__ bdst, int blk) {
    int i = blk * 256 + threadIdx.x;        // 32768 total (128x1024/4)
    int idx = i * 4;
    int r = idx >> 10;
    int c = idx & 1023;
    u16x4 o;
    if (r < rows) {
        float4 v = *(const float4*)&Wsrc[r * 1024 + c];
        o[0] = f2b(v.x); o[1] = f2b(v.y); o[2] = f2b(v.z); o[3] = f2b(v.w);
    } else {
        o[0] = 0; o[1] = 0; o[2] = 0; o[3] = 0;
    }
    *(u16x4*)&Wdst[idx] = o;
    if (i < 128) bdst[i] = (i < rows) ? bsrc[i] : 0.f;
}

// ---- W row-quant: one wave per row. q=rint(w/sw), sw=rowmax/127,
// ---- Wsum=sw*sum(q) for the asymmetric-A correction term.
__device__ __forceinline__ void wquant_row(const float* __restrict__ src,
                                           int K, u8* __restrict__ dstrow,
                                           float* __restrict__ sW,
                                           float* __restrict__ Wsum, int row_out) {
    const int lane = threadIdx.x & 63;
    const int iters = K >> 8;               // 256 floats/iter (64 lanes x float4)
    float mx = 0.f;
    for (int i = 0; i < iters; ++i) {
        float4 v = *(const float4*)&src[i * 256 + lane * 4];
        mx = fmaxf(mx, fmaxf(fmaxf(fabsf(v.x), fabsf(v.y)),
                             fmaxf(fabsf(v.z), fabsf(v.w))));
    }
#pragma unroll
    for (int off = 32; off >= 1; off >>= 1) mx = fmaxf(mx, __shfl_xor(mx, off));
    float sw  = fmaxf(mx * (1.f / 127.f), 1e-20f);
    float inv = 1.f / sw;
    int ssum = 0;
    for (int i = 0; i < iters; ++i) {
        float4 v = *(const float4*)&src[i * 256 + lane * 4];
        int q0 = q8(v.x, inv), q1 = q8(v.y, inv), q2 = q8(v.z, inv), q3 = q8(v.w, inv);
        ssum += q0 + q1 + q2 + q3;
        u32 p = (q0 & 255) | ((q1 & 255) << 8) | ((q2 & 255) << 16) | ((q3 & 255) << 24);
        *(u32*)&dstrow[i * 256 + lane * 4] = p;
    }
#pragma unroll
    for (int off = 32; off >= 1; off >>= 1) ssum += __shfl_xor(ssum, off);
    if (lane == 0) { sW[row_out] = sw; Wsum[row_out] = sw * (float)ssum; }
}

// ---- layer 1 + per-row asymmetric i8 quant of h1 ----
__device__ __forceinline__ void l1q_block(const float* __restrict__ x,
                                          const float* __restrict__ W1,
                                          const float* __restrict__ b1,
                                          u8* __restrict__ h1q,
                                          float* __restrict__ sA,
                                          float* __restrict__ muA, int blk) {
    __shared__ float wmx[4], wmn[4];
    const int t    = threadIdx.x;
    const int wave = t >> 6;
    const int lane = t & 63;
    const int b0 = blk * 16;
    const int n0 = t * 8;
    float4 wreg[8]; float breg[8];
    const float4* W14 = (const float4*)W1;
#pragma unroll
    for (int i = 0; i < 8; ++i) { wreg[i] = W14[n0 + i]; breg[i] = b1[n0 + i]; }
    for (int r = 0; r < 16; ++r) {
        int b = b0 + r;
        float4 xv = ((const float4*)x)[b];
        float v[8];
        float lmx = 0.f, lmn = 3.4e38f;
#pragma unroll
        for (int i = 0; i < 8; ++i) {
            float s = xv.x * wreg[i].x + xv.y * wreg[i].y +
                      xv.z * wreg[i].z + xv.w * wreg[i].w + breg[i];
            s = fmaxf(s, 0.f);
            v[i] = s;
            lmx = fmaxf(lmx, s); lmn = fminf(lmn, s);
        }
#pragma unroll
        for (int off = 32; off >= 1; off >>= 1) {
            lmx = fmaxf(lmx, __shfl_xor(lmx, off));
            lmn = fminf(lmn, __shfl_xor(lmn, off));
        }
        if (lane == 0) { wmx[wave] = lmx; wmn[wave] = lmn; }
        __syncthreads();
        float mx = fmaxf(fmaxf(wmx[0], wmx[1]), fmaxf(wmx[2], wmx[3]));
        float mn = fminf(fminf(wmn[0], wmn[1]), fminf(wmn[2], wmn[3]));
        float mu  = 0.5f * (mx + mn);
        float s   = fmaxf((mx - mn) * (1.f / 254.f), 1e-20f);
        float inv = 1.f / s;
        int q[8];
#pragma unroll
        for (int i = 0; i < 8; ++i) q[i] = q8(v[i] - mu, inv);
        uint2 p;
        p.x = (q[0] & 255) | ((q[1] & 255) << 8) | ((q[2] & 255) << 16) | ((q[3] & 255) << 24);
        p.y = (q[4] & 255) | ((q[5] & 255) << 8) | ((q[6] & 255) << 16) | ((q[7] & 255) << 24);
        *(uint2*)&h1q[(size_t)b * 2048 + n0] = p;
        if (t == 0) { sA[b] = s; muA[b] = mu; }
        __syncthreads();
    }
}

// ===== stage-1 prep: W2 row-quant (512 blocks, 4 rows each) + l1q (1024) ===
__global__ __launch_bounds__(256)
void k_prep1(const float* W2, u8* W2q, float* sW2, float* Wsum2,
             const float* x, const float* W1, const float* b1,
             u8* h1q, float* sA1, float* muA1) {
    int blk = blockIdx.x;
    if (blk < 512) {
        int row = blk * 4 + (threadIdx.x >> 6);
        wquant_row(W2 + (size_t)row * 2048, 2048, W2q + (size_t)row * 2048,
                   sW2, Wsum2, row);
        return;
    }
    l1q_block(x, W1, b1, h1q, sA1, muA1, blk - 512);
}

// ===== activation row-quant: one wave per row (asymmetric, centered) =======
// input bf16 [nrows][rowlen] (contiguous), output i8 same layout + s/mu[row].
__global__ __launch_bounds__(256)
void k_aquant(const u16* __restrict__ src, u8* __restrict__ dst,
              float* __restrict__ s, float* __restrict__ mu, int rowlen) {
    const int wave = threadIdx.x >> 6;
    const int lane = threadIdx.x & 63;
    const int row  = blockIdx.x * 4 + wave;
    const u16* sr = src + (size_t)row * rowlen;
    u8*       dr  = dst + (size_t)row * rowlen;
    const int nch = rowlen >> 9;            // chunks of 512 elems (8/lane)
    u16x8 vbuf[4];
    float mx = -3.4e38f, mn = 3.4e38f;
    for (int c = 0; c < nch; ++c) {
        u16x8 v = *(const u16x8*)&sr[c * 512 + lane * 8];
        vbuf[c] = v;
#pragma unroll
        for (int i = 0; i < 8; ++i) {
            float f = b2f(v[i]);
            mx = fmaxf(mx, f); mn = fminf(mn, f);
        }
    }
#pragma unroll
    for (int off = 32; off >= 1; off >>= 1) {
        mx = fmaxf(mx, __shfl_xor(mx, off));
        mn = fminf(mn, __shfl_xor(mn, off));
    }
    float m  = 0.5f * (mx + mn);
    float sc = fmaxf((mx - mn) * (1.f / 254.f), 1e-20f);
    float inv = 1.f / sc;
    for (int c = 0; c < nch; ++c) {
        u16x8 v = vbuf[c];
        int q[8];
#pragma unroll
        for (int i = 0; i < 8; ++i) q[i] = q8(b2f(v[i]) - m, inv);
        uint2 p;
        p.x = (q[0] & 255) | ((q[1] & 255) << 8) | ((q[2] & 255) << 16) | ((q[3] & 255) << 24);
        p.y = (q[4] & 255) | ((q[5] & 255) << 8) | ((q[6] & 255) << 16) | ((q[7] & 255) << 24);
        *(uint2*)&dr[c * 512 + lane * 8] = p;
    }
    if (lane == 0) { s[row] = sc; mu[row] = m; }
}

// ===== backfill prep (extra blocks inside the L2 GEMM dispatch) ============
// W3q (W31||W32 rows, 512 blk) | W41q 256 | W42q 256 | W51p 128 | W52p 128 |
// b3c 8  = 1288 blocks
__device__ __forceinline__ void backfill_prep(
        int pblk,
        const float* W31, const float* W32, u8* W3q, float* sW3, float* Wsum3,
        const float* W41, u8* W41q, float* sW41, float* Ws41,
        const float* W42, u8* W42q, float* sW42, float* Ws42,
        const float* W51, u16* W51p, const float* b51, float* b51p,
        const float* W52, u16* W52p, const float* b52, float* b52p,
        const float* b31, const float* b32, float* b3c) {
    if (pblk < 512) {
        int row = pblk * 4 + (threadIdx.x >> 6);
        const float* src = (row < 1024) ? W31 + (size_t)row * 2048
                                        : W32 + (size_t)(row - 1024) * 2048;
        wquant_row(src, 2048, W3q + (size_t)row * 2048, sW3, Wsum3, row);
        return;
    }
    pblk -= 512;
    if (pblk < 256) {
        int row = pblk * 4 + (threadIdx.x >> 6);
        wquant_row(W41 + (size_t)row * 1024, 1024, W41q + (size_t)row * 1024,
                   sW41, Ws41, row);
        return;
    }
    pblk -= 256;
    if (pblk < 256) {
        int row = pblk * 4 + (threadIdx.x >> 6);
        wquant_row(W42 + (size_t)row * 1024, 1024, W42q + (size_t)row * 1024,
                   sW42, Ws42, row);
        return;
    }
    pblk -= 256;
    if (pblk < 128) { pad_block(W51, 20, W51p, b51, b51p, pblk); return; }
    pblk -= 128;
    if (pblk < 128) { pad_block(W52, 11, W52p, b52, b52p, pblk); return; }
    pblk -= 128;
    if (pblk < 8) {
        int i = pblk * 256 + threadIdx.x;
        b3c[i] = (i < 1024) ? b31[i] : b32[i - 1024];
    }
}

// ================= i8 MFMA GEMM: 256x128 tile, BK=128 i8 ===================
// C = relu(deq(Aq @ Wq^T) + b). A per-row asymmetric (mu,s; scale index =
// row*sstride via base-pointer offset), W per-row symmetric (sW, Wsum).
// Epilogue: v = accI*(sA*sW) + muA*Wsum + bias. lda = A row stride (elems).
// Verified i8 fragment layout (R9): natural doubling of bf16 32x32 pattern.
// Optional second GEMM for swizzled by >= split; backfill beyond gemmY.
__global__ __launch_bounds__(256, 2)
void k_gemmq(const u8* __restrict__ A, const u8* __restrict__ Wq,
             const float* __restrict__ sA, const float* __restrict__ muA,
             const float* __restrict__ sW, const float* __restrict__ Wsum,
             const float* __restrict__ bias, u16* __restrict__ C,
             int K, int lda, int ldc, int sstride, int gemmY,
             const u8* A2, const u8* Wq2,
             const float* sA2, const float* muA2,
             const float* sW2, const float* Wsum2,
             const float* bias2, u16* C2, int split,
             const float* W31, const float* W32, u8* W3q, float* sW3, float* Wsum3,
             const float* W41, u8* W41q, float* sW41, float* Ws41,
             const float* W42, u8* W42q, float* sW42, float* Ws42,
             const float* W51, u16* W51p, const float* b51, float* b51p,
             const float* W52, u16* W52p, const float* b52, float* b52p,
             const float* b31, const float* b32, float* b3c) {
    const int ngemm = gemmY * gridDim.x;
    int flat = blockIdx.y * gridDim.x + blockIdx.x;
    if (flat >= ngemm) {
        backfill_prep(flat - ngemm, W31, W32, W3q, sW3, Wsum3,
                      W41, W41q, sW41, Ws41, W42, W42q, sW42, Ws42,
                      W51, W51p, b51, b51p, W52, W52p, b52, b52p,
                      b31, b32, b3c);
        return;
    }

    __shared__ __align__(16) u8 As[256 * 128];  // 32 KB
    __shared__ __align__(16) u8 Ws[128 * 128];  // 16 KB

    const int tid  = threadIdx.x;
    const int wave = tid >> 6;
    const int lane = tid & 63;

    int xcd = flat & 7;
    int p   = flat >> 3;
    int bx  = p % gridDim.x;
    int by  = (p / gridDim.x) * 8 + xcd;
    if (A2 != nullptr && by >= split) {
        A = A2; Wq = Wq2; sA = sA2; muA = muA2; sW = sW2; Wsum = Wsum2;
        bias = bias2; C = C2; by -= split;
    }
    const int bm = by * 256;
    const int bn = bx * 128;

    const int srow = lane >> 3;                     // 0..7
    const int sg   = ((lane & 7) ^ srow) * 16;      // swizzled global byte offset

    const int wm    = (wave & 1) * 128;
    const int wn    = (wave >> 1) * 64;
    const int row32 = lane & 31;
    const int half  = lane >> 5;

    intx16 acc[4][2];
#pragma unroll
    for (int i = 0; i < 4; ++i)
#pragma unroll
        for (int j = 0; j < 2; ++j)
#pragma unroll
            for (int r = 0; r < 16; ++r) acc[i][j][r] = 0;

    for (int k0 = 0; k0 < K; k0 += 128) {
#pragma unroll
        for (int i = 0; i < 8; ++i) {
            int ci = wave * 8 + i;              // 32 chunks of 8 rows (A)
            int r  = ci * 8 + srow;
            const u8* ga = A + (size_t)(bm + r) * lda + k0 + sg;
            __builtin_amdgcn_global_load_lds(
                (const __attribute__((address_space(1))) void*)ga,
                (__attribute__((address_space(3))) void*)&As[ci * 1024], 16, 0, 0);
        }
#pragma unroll
        for (int i = 0; i < 4; ++i) {
            int ci = wave * 4 + i;              // 16 chunks of 8 rows (W)
            int r  = ci * 8 + srow;
            const u8* gw = Wq + (size_t)(bn + r) * K + k0 + sg;
            __builtin_amdgcn_global_load_lds(
                (const __attribute__((address_space(1))) void*)gw,
                (__attribute__((address_space(3))) void*)&Ws[ci * 1024], 16, 0, 0);
        }
        __syncthreads();

#pragma unroll
        for (int s = 0; s < 4; ++s) {
            const int c = s * 2 + half;         // logical 16B chunk 0..7
            intx4 af[4], bf[2];
#pragma unroll
            for (int i = 0; i < 4; ++i) {
                int r = wm + i * 32 + row32;
                af[i] = *(const intx4*)&As[r * 128 + ((c ^ (r & 7)) * 16)];
            }
#pragma unroll
            for (int j = 0; j < 2; ++j) {
                int r = wn + j * 32 + row32;
                bf[j] = *(const intx4*)&Ws[r * 128 + ((c ^ (r & 7)) * 16)];
            }
#pragma unroll
            for (int i = 0; i < 4; ++i)
#pragma unroll
                for (int j = 0; j < 2; ++j)
                    acc[i][j] = __builtin_amdgcn_mfma_i32_32x32x32_i8(
                        af[i], bf[j], acc[i][j], 0, 0, 0);
        }
        __syncthreads();
    }

    // epilogue: dequant. C/D layout col=lane&31, row=(r&3)+8*(r>>2)+4*half
    float sWv[2], Wsv[2], bv[2];
#pragma unroll
    for (int j = 0; j < 2; ++j) {
        int col = bn + wn + j * 32 + row32;
        sWv[j] = sW[col]; Wsv[j] = Wsum[col]; bv[j] = bias[col];
    }
#pragma unroll
    for (int i = 0; i < 4; ++i)
#pragma unroll
        for (int r = 0; r < 16; ++r) {
            int row = bm + wm + i * 32 + (r & 3) + 8 * (r >> 2) + 4 * half;
            float sa = sA[row * sstride], mu = muA[row * sstride];
#pragma unroll
            for (int j = 0; j < 2; ++j) {
                int col = bn + wn + j * 32 + row32;
                float v = (float)acc[i][j][r] * (sa * sWv[j]) + mu * Wsv[j] + bv[j];
                v = fmaxf(v, 0.f);
                C[(size_t)row * ldc + col] = f2b(v);
            }
        }
}

// ====== fused heads + physics/QP/softmax epilogue (bf16, unchanged) ========
__global__ __launch_bounds__(256, 2)
void k_heads_final(const u16* __restrict__ hbuf,       // bufB: h41 || h42
                   const u16* __restrict__ W51p, const float* __restrict__ b51p,
                   const u16* __restrict__ W52p, const float* __restrict__ b52p,
                   const float* __restrict__ x, const float* __restrict__ mean,
                   const float* __restrict__ std_,
                   const float* __restrict__ mean_label,
                   const float* __restrict__ std_label,
                   const float* __restrict__ wt, float* __restrict__ out) {
    __shared__ __align__(16) u16 As[128 * 64];     // 16 KB
    __shared__ __align__(16) u16 Ws[128 * 64];     // 16 KB
    __shared__ float x51s[128 * 20];               // 10 KB
    __shared__ float x52s[128 * 11];               // 5.5 KB

    const int tid  = threadIdx.x;
    const int wave = tid >> 6;
    const int lane = tid & 63;
    const int bm   = blockIdx.x * 128;

    const int srow = lane >> 3;
    const int sg   = ((lane & 7) ^ srow) * 8;

    const int wm    = (wave & 1) * 64;
    const int wn    = (wave >> 1) * 64;
    const int row32 = lane & 31;
    const int half  = lane >> 5;

    auto run_gemm = [&](const u16* Abase, const u16* Wp, const float* bp,
                        float* dst, int ncols) {
        floatx16 acc[2][2];
#pragma unroll
        for (int i = 0; i < 2; ++i)
#pragma unroll
            for (int j = 0; j < 2; ++j)
#pragma unroll
                for (int r = 0; r < 16; ++r) acc[i][j][r] = 0.f;

        for (int k0 = 0; k0 < 1024; k0 += 64) {
#pragma unroll
            for (int i = 0; i < 4; ++i) {
                int ci = wave * 4 + i;
                int r  = ci * 8 + srow;
                const u16* ga = Abase + (size_t)(bm + r) * 2048 + k0 + sg;
                __builtin_amdgcn_global_load_lds(
                    (const __attribute__((address_space(1))) void*)ga,
                    (__attribute__((address_space(3))) void*)&As[ci * 512], 16, 0, 0);
                const u16* gw = Wp + (size_t)r * 1024 + k0 + sg;
                __builtin_amdgcn_global_load_lds(
                    (const __attribute__((address_space(1))) void*)gw,
                    (__attribute__((address_space(3))) void*)&Ws[ci * 512], 16, 0, 0);
            }
            __syncthreads();
#pragma unroll
            for (int s = 0; s < 4; ++s) {
                const int c = s * 2 + half;
                short8 a0, a1, b0, b1;
                { int r = wm + row32;       a0 = *(const short8*)&As[r * 64 + ((c ^ (r & 7)) * 8)]; }
                { int r = wm + 32 + row32;  a1 = *(const short8*)&As[r * 64 + ((c ^ (r & 7)) * 8)]; }
                { int r = wn + row32;       b0 = *(const short8*)&Ws[r * 64 + ((c ^ (r & 7)) * 8)]; }
                { int r = wn + 32 + row32;  b1 = *(const short8*)&Ws[r * 64 + ((c ^ (r & 7)) * 8)]; }
                acc[0][0] = __builtin_amdgcn_mfma_f32_32x32x16_bf16(a0, b0, acc[0][0], 0, 0, 0);
                acc[0][1] = __builtin_amdgcn_mfma_f32_32x32x16_bf16(a0, b1, acc[0][1], 0, 0, 0);
                acc[1][0] = __builtin_amdgcn_mfma_f32_32x32x16_bf16(a1, b0, acc[1][0], 0, 0, 0);
                acc[1][1] = __builtin_amdgcn_mfma_f32_32x32x16_bf16(a1, b1, acc[1][1], 0, 0, 0);
            }
            __syncthreads();
        }
#pragma unroll
        for (int i = 0; i < 2; ++i)
#pragma unroll
            for (int j = 0; j < 2; ++j) {
                int col = wn + j * 32 + row32;
                if (col < ncols) {
                    float bj = bp[col];
#pragma unroll
                    for (int r = 0; r < 16; ++r) {
                        int row = wm + i * 32 + (r & 3) + 8 * (r >> 2) + 4 * half;
                        dst[row * ncols + col] = acc[i][j][r] + bj;
                    }
                }
            }
    };

    run_gemm(hbuf,        W51p, b51p, x51s, 20);
    run_gemm(hbuf + 1024, W52p, b52p, x52s, 11);
    __syncthreads();

    if (tid < 128) {
        int b = bm + tid;

        float w[10], m = -1e30f;
#pragma unroll
        for (int h = 0; h < 10; ++h) { w[h] = wt[h]; m = fmaxf(m, w[h]); }
        float ssum = 0.f;
#pragma unroll
        for (int h = 0; h < 10; ++h) { w[h] = __expf(w[h] - m); ssum += w[h]; }
        float winv = 1.f / ssum;

        float4 xv = ((const float4*)x)[b];
        float th1 = xv.x * std_[0] + mean[0];
        float w1v = xv.y * std_[1] + mean[1];
        float th2 = xv.z * std_[2] + mean[2];
        float w2v = xv.w * std_[3] + mean[3];
        float s1 = sinf(th1), c1 = cosf(th1);
        float s2 = sinf(th2), c2 = cosf(th2);
        float px = 3.f * c1 + 3.f * c2 - 0.f;
        float py = 3.f * s1 + 3.f * s2 - 7.f;
        float vx = -3.f * s1 * w1v - 3.f * s2 * w2v;
        float vy =  3.f * c1 * w1v + 3.f * c2 * w2v;
        float barrier = px * px + py * py - 16.f;
        float b_dot = 2.f * (px * vx + py * vy);
        float Lf2b = 2.f * vx * vx + 2.f * vy * vy
                   + 2.f * px * (-3.f * c1 * w1v * w1v - 3.f * c2 * w2v * w2v)
                   + 2.f * py * (-3.f * s1 * w1v * w1v - 3.f * s2 * w2v * w2v);
        float g1 = 2.f * px * (-3.f * s1) + 2.f * py * (3.f * c1);
        float g2 = 2.f * px * (-3.f * s2) + 2.f * py * (3.f * c2);
        float Gx = -g1, Gy = -g2;
        float Gdot = Gx * Gx + Gy * Gy;

        float alpha = 4.f / (1.f + expf(-x52s[tid * 11 + 0]));

        float rx = 0.f, ry = 0.f;
#pragma unroll
        for (int h = 0; h < 10; ++h) {
            float r0 = x51s[tid * 20 + 2 * h];
            float r1 = x51s[tid * 20 + 2 * h + 1];
            float beta = 4.f / (1.f + expf(-x52s[tid * 11 + 1 + h]));
            float hh = Lf2b + (alpha + beta) * b_dot + alpha * beta * barrier;
            float ux = -r0, uy = -r1;
            float viol = ux * Gx + uy * Gy - hh;
            float lam = fmaxf(viol / Gdot, 0.f);
            float sx = ux - lam * Gx;
            float sy = uy - lam * Gy;
            float wk = w[h] * winv;
            rx += wk * sx; ry += wk * sy;
        }
        out[2 * b]     = (rx - mean_label[0]) / std_label[0];
        out[2 * b + 1] = (ry - mean_label[1]) / std_label[1];
    }
}

extern "C" void kernel_launch(void* const* d_in, const int* in_sizes, int n_in,
                              void* d_out, int out_size, void* d_ws, size_t ws_size,
                              hipStream_t stream) {
    const float* x    = (const float*)d_in[0];
    const float* mean = (const float*)d_in[2];
    const float* std_ = (const float*)d_in[3];
    const float* mean_label = (const float*)d_in[4];
    const float* std_label  = (const float*)d_in[5];
    const float* W1  = (const float*)d_in[6];
    const float* b1  = (const float*)d_in[7];
    const float* W2  = (const float*)d_in[8];
    const float* b2  = (const float*)d_in[9];
    const float* W31 = (const float*)d_in[10];
    const float* b31 = (const float*)d_in[11];
    const float* W32 = (const float*)d_in[12];
    const float* b32 = (const float*)d_in[13];
    const float* W41 = (const float*)d_in[14];
    const float* b41 = (const float*)d_in[15];
    const float* W42 = (const float*)d_in[16];
    const float* b42 = (const float*)d_in[17];
    const float* W51 = (const float*)d_in[18];
    const float* b51 = (const float*)d_in[19];
    const float* W52 = (const float*)d_in[20];
    const float* b52 = (const float*)d_in[21];
    const float* wt  = (const float*)d_in[22];

    const int B = in_sizes[0] / 4;       // 16384

    char* wsp = (char*)d_ws;
    size_t off = 0;
    auto alloc = [&](size_t bytes) {
        void* p = wsp + off;
        off += (bytes + 255) & ~(size_t)255;
        return p;
    };
    u8*    W2q   = (u8*)   alloc((size_t)2048 * 2048);
    float* sW2   = (float*)alloc(2048 * 4);
    float* Wsum2 = (float*)alloc(2048 * 4);
    u8*    h1q   = (u8*)   alloc((size_t)B * 2048);
    float* sA1   = (float*)alloc((size_t)B * 4);
    float* muA1  = (float*)alloc((size_t)B * 4);
    u8*    W3q   = (u8*)   alloc((size_t)2048 * 2048);
    float* sW3   = (float*)alloc(2048 * 4);
    float* Wsum3 = (float*)alloc(2048 * 4);
    u8*    W41q  = (u8*)   alloc((size_t)1024 * 1024);
    float* sW41  = (float*)alloc(1024 * 4);
    float* Ws41  = (float*)alloc(1024 * 4);
    u8*    W42q  = (u8*)   alloc((size_t)1024 * 1024);
    float* sW42  = (float*)alloc(1024 * 4);
    float* Ws42  = (float*)alloc(1024 * 4);
    u16*   W51p  = (u16*)  alloc((size_t)128 * 1024 * 2);
    u16*   W52p  = (u16*)  alloc((size_t)128 * 1024 * 2);
    float* b51p  = (float*)alloc(512);
    float* b52p  = (float*)alloc(512);
    float* b3c   = (float*)alloc(2048 * 4);
    u8*    h2q   = (u8*)   alloc((size_t)B * 2048);
    float* s2a   = (float*)alloc((size_t)B * 4);
    float* mu2a  = (float*)alloc((size_t)B * 4);
    u8*    h34q  = (u8*)   alloc((size_t)B * 2048);
    float* s34   = (float*)alloc((size_t)2 * B * 4);
    float* mu34  = (float*)alloc((size_t)2 * B * 4);
    u16*   bufA  = (u16*)  alloc((size_t)B * 2048 * 2);   // h31||h32 (bf16)
    u16*   bufB  = (u16*)  alloc((size_t)B * 2048 * 2);   // h2 -> h41||h42 (bf16)
    const u8* NUL8 = nullptr;

    // stage-1 prep: W2 row-quant + layer-1-with-quant (gates L2)
    k_prep1<<<1536, 256, 0, stream>>>(W2, W2q, sW2, Wsum2,
                                      x, W1, b1, h1q, sA1, muA1);

    // L2 (i8): h2 = relu(deq(h1q @ W2q^T) + b2)  -> bufB (bf16)
    // grid: 16 x (64 + 81); backfill = 1296 slots for 1288 prep blocks
    k_gemmq<<<dim3(16, 64 + 81), 256, 0, stream>>>(
        h1q, W2q, sA1, muA1, sW2, Wsum2, b2, bufB, 2048, 2048, 2048, 1, 64,
        NUL8, NUL8, nullptr, nullptr, nullptr, nullptr, nullptr, nullptr, 0,
        W31, W32, W3q, sW3, Wsum3,
        W41, W41q, sW41, Ws41, W42, W42q, sW42, Ws42,
        W51, W51p, b51, b51p, W52, W52p, b52, b52p, b31, b32, b3c);

    // quantize h2 rows (B rows of 2048)
    k_aquant<<<B / 4, 256, 0, stream>>>(bufB, h2q, s2a, mu2a, 2048);

    // L3 (i8): h31||h32 = relu(deq(h2q @ W3q^T) + b3c) -> bufA (bf16)
    k_gemmq<<<dim3(16, 64), 256, 0, stream>>>(
        h2q, W3q, s2a, mu2a, sW3, Wsum3, b3c, bufA, 2048, 2048, 2048, 1, 64,
        NUL8, NUL8, nullptr, nullptr, nullptr, nullptr, nullptr, nullptr, 0,
        nullptr, nullptr, nullptr, nullptr, nullptr,
        nullptr, nullptr, nullptr, nullptr, nullptr, nullptr, nullptr, nullptr,
        nullptr, nullptr, nullptr, nullptr, nullptr, nullptr, nullptr, nullptr,
        nullptr, nullptr, nullptr);

    // quantize h31/h32 halves independently (2B rows of 1024)
    k_aquant<<<2 * B / 4, 256, 0, stream>>>(bufA, h34q, s34, mu34, 1024);

    // L4 (i8, two GEMMs): h41 -> bufB[:, :1024]; h42 -> bufB[:, 1024:]
    k_gemmq<<<dim3(8, 128), 256, 0, stream>>>(
        h34q, W41q, s34, mu34, sW41, Ws41, b41, bufB,
        1024, 2048, 2048, 2, 128,
        h34q + 1024, W42q, s34 + 1, mu34 + 1, sW42, Ws42, b42, bufB + 1024, 64,
        nullptr, nullptr, nullptr, nullptr, nullptr,
        nullptr, nullptr, nullptr, nullptr, nullptr, nullptr, nullptr, nullptr,
        nullptr, nullptr, nullptr, nullptr, nullptr, nullptr, nullptr, nullptr,
        nullptr, nullptr, nullptr);

    // fused heads GEMMs + physics/QP/softmax epilogue (bf16)
    k_heads_final<<<B / 128, 256, 0, stream>>>(
        bufB, W51p, b51p, W52p, b52p, x, mean, std_,
        mean_label, std_label, wt, (float*)d_out);
}

// Round 11
// 409.632 us; speedup vs baseline: 1.6720x; 1.6720x over previous
//
#include <hip/hip_runtime.h>

typedef unsigned short u16;
typedef unsigned char  u8;
typedef unsigned int   u32;
typedef __attribute__((ext_vector_type(8)))  short short8;   // 8 bf16 (4 VGPRs)
typedef __attribute__((ext_vector_type(16))) float floatx16; // 32x32 MFMA C/D f32
typedef __attribute__((ext_vector_type(4)))  int   intx4;    // 16 i8 (4 VGPRs)
typedef __attribute__((ext_vector_type(16))) int   intx16;   // 32x32 i8 MFMA C/D
typedef __attribute__((ext_vector_type(8)))  u16   u16x8;
typedef __attribute__((ext_vector_type(4)))  u16   u16x4;

__device__ __forceinline__ u16 f2b(float f) {
    u32 u = __float_as_uint(f);
    u = (u + 0x7FFFu + ((u >> 16) & 1u)) >> 16;
    return (u16)u;
}
__device__ __forceinline__ float b2f(u16 h) {
    return __uint_as_float(((u32)h) << 16);
}
__device__ __forceinline__ int q8(float v, float inv) {
    return __float2int_rn(fminf(fmaxf(v * inv, -127.f), 127.f));
}

// ================= prep building blocks (256-thread granularity) ===========
__device__ __forceinline__ void pad_block(const float* __restrict__ Wsrc, int rows,
                                          u16* __restrict__ Wdst,
                                          const float* __restrict__ bsrc,
                                          float* __restrict__ bdst, int blk) {
    int i = blk * 256 + threadIdx.x;        // 32768 total (128x1024/4)
    int idx = i * 4;
    int r = idx >> 10;
    int c = idx & 1023;
    u16x4 o;
    if (r < rows) {
        float4 v = *(const float4*)&Wsrc[r * 1024 + c];
        o[0] = f2b(v.x); o[1] = f2b(v.y); o[2] = f2b(v.z); o[3] = f2b(v.w);
    } else {
        o[0] = 0; o[1] = 0; o[2] = 0; o[3] = 0;
    }
    *(u16x4*)&Wdst[idx] = o;
    if (i < 128) bdst[i] = (i < rows) ? bsrc[i] : 0.f;
}

// ---- W row-quant: one wave per row. q=rint(w/sw), sw=rowmax/127,
// ---- Wsum=sw*sum(q) for the asymmetric-A correction term.
__device__ __forceinline__ void wquant_row(const float* __restrict__ src,
                                           int K, u8* __restrict__ dstrow,
                                           float* __restrict__ sW,
                                           float* __restrict__ Wsum, int row_out) {
    const int lane = threadIdx.x & 63;
    const int iters = K >> 8;               // 256 floats/iter (64 lanes x float4)
    float mx = 0.f;
    for (int i = 0; i < iters; ++i) {
        float4 v = *(const float4*)&src[i * 256 + lane * 4];
        mx = fmaxf(mx, fmaxf(fmaxf(fabsf(v.x), fabsf(v.y)),
                             fmaxf(fabsf(v.z), fabsf(v.w))));
    }
#pragma unroll
    for (int off = 32; off >= 1; off >>= 1) mx = fmaxf(mx, __shfl_xor(mx, off));
    float sw  = fmaxf(mx * (1.f / 127.f), 1e-20f);
    float inv = 1.f / sw;
    int ssum = 0;
    for (int i = 0; i < iters; ++i) {
        float4 v = *(const float4*)&src[i * 256 + lane * 4];
        int q0 = q8(v.x, inv), q1 = q8(v.y, inv), q2 = q8(v.z, inv), q3 = q8(v.w, inv);
        ssum += q0 + q1 + q2 + q3;
        u32 p = (q0 & 255) | ((q1 & 255) << 8) | ((q2 & 255) << 16) | ((q3 & 255) << 24);
        *(u32*)&dstrow[i * 256 + lane * 4] = p;
    }
#pragma unroll
    for (int off = 32; off >= 1; off >>= 1) ssum += __shfl_xor(ssum, off);
    if (lane == 0) { sW[row_out] = sw; Wsum[row_out] = sw * (float)ssum; }
}

// ---- layer 1 + per-row asymmetric i8 quant of h1 ----
__device__ __forceinline__ void l1q_block(const float* __restrict__ x,
                                          const float* __restrict__ W1,
                                          const float* __restrict__ b1,
                                          u8* __restrict__ h1q,
                                          float* __restrict__ sA,
                                          float* __restrict__ muA, int blk) {
    __shared__ float wmx[4], wmn[4];
    const int t    = threadIdx.x;
    const int wave = t >> 6;
    const int lane = t & 63;
    const int b0 = blk * 16;
    const int n0 = t * 8;
    float4 wreg[8]; float breg[8];
    const float4* W14 = (const float4*)W1;
#pragma unroll
    for (int i = 0; i < 8; ++i) { wreg[i] = W14[n0 + i]; breg[i] = b1[n0 + i]; }
    for (int r = 0; r < 16; ++r) {
        int b = b0 + r;
        float4 xv = ((const float4*)x)[b];
        float v[8];
        float lmx = 0.f, lmn = 3.4e38f;
#pragma unroll
        for (int i = 0; i < 8; ++i) {
            float s = xv.x * wreg[i].x + xv.y * wreg[i].y +
                      xv.z * wreg[i].z + xv.w * wreg[i].w + breg[i];
            s = fmaxf(s, 0.f);
            v[i] = s;
            lmx = fmaxf(lmx, s); lmn = fminf(lmn, s);
        }
#pragma unroll
        for (int off = 32; off >= 1; off >>= 1) {
            lmx = fmaxf(lmx, __shfl_xor(lmx, off));
            lmn = fminf(lmn, __shfl_xor(lmn, off));
        }
        if (lane == 0) { wmx[wave] = lmx; wmn[wave] = lmn; }
        __syncthreads();
        float mx = fmaxf(fmaxf(wmx[0], wmx[1]), fmaxf(wmx[2], wmx[3]));
        float mn = fminf(fminf(wmn[0], wmn[1]), fminf(wmn[2], wmn[3]));
        float mu  = 0.5f * (mx + mn);
        float s   = fmaxf((mx - mn) * (1.f / 254.f), 1e-20f);
        float inv = 1.f / s;
        int q[8];
#pragma unroll
        for (int i = 0; i < 8; ++i) q[i] = q8(v[i] - mu, inv);
        uint2 p;
        p.x = (q[0] & 255) | ((q[1] & 255) << 8) | ((q[2] & 255) << 16) | ((q[3] & 255) << 24);
        p.y = (q[4] & 255) | ((q[5] & 255) << 8) | ((q[6] & 255) << 16) | ((q[7] & 255) << 24);
        *(uint2*)&h1q[(size_t)b * 2048 + n0] = p;
        if (t == 0) { sA[b] = s; muA[b] = mu; }
        __syncthreads();
    }
}

// ===== stage-1 prep: W2 row-quant (512 blocks, 4 rows each) + l1q (1024) ===
__global__ __launch_bounds__(256)
void k_prep1(const float* W2, u8* W2q, float* sW2, float* Wsum2,
             const float* x, const float* W1, const float* b1,
             u8* h1q, float* sA1, float* muA1) {
    int blk = blockIdx.x;
    if (blk < 512) {
        int row = blk * 4 + (threadIdx.x >> 6);
        wquant_row(W2 + (size_t)row * 2048, 2048, W2q + (size_t)row * 2048,
                   sW2, Wsum2, row);
        return;
    }
    l1q_block(x, W1, b1, h1q, sA1, muA1, blk - 512);
}

// ===== activation row-quant: one wave per row (asymmetric, centered) =======
// input bf16 [nrows][NCH*512] (contiguous), output i8 same layout + s/mu.
// NCH is a compile-time constant so vbuf is fully unrolled into VGPRs
// (runtime bound in R10 spilled vbuf to scratch -> 169us; this is the fix).
template<int NCH>
__global__ __launch_bounds__(256)
void k_aquant(const u16* __restrict__ src, u8* __restrict__ dst,
              float* __restrict__ s, float* __restrict__ mu) {
    const int wave = threadIdx.x >> 6;
    const int lane = threadIdx.x & 63;
    const int row  = blockIdx.x * 4 + wave;
    const int rowlen = NCH * 512;
    const u16* sr = src + (size_t)row * rowlen;
    u8*       dr  = dst + (size_t)row * rowlen;
    u16x8 vbuf[NCH];
    float mx = -3.4e38f, mn = 3.4e38f;
#pragma unroll
    for (int c = 0; c < NCH; ++c) {
        u16x8 v = *(const u16x8*)&sr[c * 512 + lane * 8];
        vbuf[c] = v;
#pragma unroll
        for (int i = 0; i < 8; ++i) {
            float f = b2f(v[i]);
            mx = fmaxf(mx, f); mn = fminf(mn, f);
        }
    }
#pragma unroll
    for (int off = 32; off >= 1; off >>= 1) {
        mx = fmaxf(mx, __shfl_xor(mx, off));
        mn = fminf(mn, __shfl_xor(mn, off));
    }
    float m  = 0.5f * (mx + mn);
    float sc = fmaxf((mx - mn) * (1.f / 254.f), 1e-20f);
    float inv = 1.f / sc;
#pragma unroll
    for (int c = 0; c < NCH; ++c) {
        u16x8 v = vbuf[c];
        int q[8];
#pragma unroll
        for (int i = 0; i < 8; ++i) q[i] = q8(b2f(v[i]) - m, inv);
        uint2 p;
        p.x = (q[0] & 255) | ((q[1] & 255) << 8) | ((q[2] & 255) << 16) | ((q[3] & 255) << 24);
        p.y = (q[4] & 255) | ((q[5] & 255) << 8) | ((q[6] & 255) << 16) | ((q[7] & 255) << 24);
        *(uint2*)&dr[c * 512 + lane * 8] = p;
    }
    if (lane == 0) { s[row] = sc; mu[row] = m; }
}

// ===== backfill prep (extra blocks inside the L2 GEMM dispatch) ============
// W3q (W31||W32 rows, 512 blk) | W41q 256 | W42q 256 | W51p 128 | W52p 128 |
// b3c 8  = 1288 blocks
__device__ __forceinline__ void backfill_prep(
        int pblk,
        const float* W31, const float* W32, u8* W3q, float* sW3, float* Wsum3,
        const float* W41, u8* W41q, float* sW41, float* Ws41,
        const float* W42, u8* W42q, float* sW42, float* Ws42,
        const float* W51, u16* W51p, const float* b51, float* b51p,
        const float* W52, u16* W52p, const float* b52, float* b52p,
        const float* b31, const float* b32, float* b3c) {
    if (pblk < 512) {
        int row = pblk * 4 + (threadIdx.x >> 6);
        const float* src = (row < 1024) ? W31 + (size_t)row * 2048
                                        : W32 + (size_t)(row - 1024) * 2048;
        wquant_row(src, 2048, W3q + (size_t)row * 2048, sW3, Wsum3, row);
        return;
    }
    pblk -= 512;
    if (pblk < 256) {
        int row = pblk * 4 + (threadIdx.x >> 6);
        wquant_row(W41 + (size_t)row * 1024, 1024, W41q + (size_t)row * 1024,
                   sW41, Ws41, row);
        return;
    }
    pblk -= 256;
    if (pblk < 256) {
        int row = pblk * 4 + (threadIdx.x >> 6);
        wquant_row(W42 + (size_t)row * 1024, 1024, W42q + (size_t)row * 1024,
                   sW42, Ws42, row);
        return;
    }
    pblk -= 256;
    if (pblk < 128) { pad_block(W51, 20, W51p, b51, b51p, pblk); return; }
    pblk -= 128;
    if (pblk < 128) { pad_block(W52, 11, W52p, b52, b52p, pblk); return; }
    pblk -= 128;
    if (pblk < 8) {
        int i = pblk * 256 + threadIdx.x;
        b3c[i] = (i < 1024) ? b31[i] : b32[i - 1024];
    }
}

// ================= i8 MFMA GEMM: 256x128 tile, BK=128 i8 ===================
// C = relu(deq(Aq @ Wq^T) + b). A per-row asymmetric (mu,s; scale index =
// row*sstride via base-pointer offset), W per-row symmetric (sW, Wsum).
// Epilogue: v = accI*(sA*sW) + muA*Wsum + bias. lda = A row stride (elems).
// Verified i8 fragment layout (R9): natural doubling of bf16 32x32 pattern.
// Optional second GEMM for swizzled by >= split; backfill beyond gemmY.
__global__ __launch_bounds__(256, 2)
void k_gemmq(const u8* __restrict__ A, const u8* __restrict__ Wq,
             const float* __restrict__ sA, const float* __restrict__ muA,
             const float* __restrict__ sW, const float* __restrict__ Wsum,
             const float* __restrict__ bias, u16* __restrict__ C,
             int K, int lda, int ldc, int sstride, int gemmY,
             const u8* A2, const u8* Wq2,
             const float* sA2, const float* muA2,
             const float* sW2, const float* Wsum2,
             const float* bias2, u16* C2, int split,
             const float* W31, const float* W32, u8* W3q, float* sW3, float* Wsum3,
             const float* W41, u8* W41q, float* sW41, float* Ws41,
             const float* W42, u8* W42q, float* sW42, float* Ws42,
             const float* W51, u16* W51p, const float* b51, float* b51p,
             const float* W52, u16* W52p, const float* b52, float* b52p,
             const float* b31, const float* b32, float* b3c) {
    const int ngemm = gemmY * gridDim.x;
    int flat = blockIdx.y * gridDim.x + blockIdx.x;
    if (flat >= ngemm) {
        backfill_prep(flat - ngemm, W31, W32, W3q, sW3, Wsum3,
                      W41, W41q, sW41, Ws41, W42, W42q, sW42, Ws42,
                      W51, W51p, b51, b51p, W52, W52p, b52, b52p,
                      b31, b32, b3c);
        return;
    }

    __shared__ __align__(16) u8 As[256 * 128];  // 32 KB
    __shared__ __align__(16) u8 Ws[128 * 128];  // 16 KB

    const int tid  = threadIdx.x;
    const int wave = tid >> 6;
    const int lane = tid & 63;

    int xcd = flat & 7;
    int p   = flat >> 3;
    int bx  = p % gridDim.x;
    int by  = (p / gridDim.x) * 8 + xcd;
    if (A2 != nullptr && by >= split) {
        A = A2; Wq = Wq2; sA = sA2; muA = muA2; sW = sW2; Wsum = Wsum2;
        bias = bias2; C = C2; by -= split;
    }
    const int bm = by * 256;
    const int bn = bx * 128;

    const int srow = lane >> 3;                     // 0..7
    const int sg   = ((lane & 7) ^ srow) * 16;      // swizzled global byte offset

    const int wm    = (wave & 1) * 128;
    const int wn    = (wave >> 1) * 64;
    const int row32 = lane & 31;
    const int half  = lane >> 5;

    intx16 acc[4][2];
#pragma unroll
    for (int i = 0; i < 4; ++i)
#pragma unroll
        for (int j = 0; j < 2; ++j)
#pragma unroll
            for (int r = 0; r < 16; ++r) acc[i][j][r] = 0;

    for (int k0 = 0; k0 < K; k0 += 128) {
#pragma unroll
        for (int i = 0; i < 8; ++i) {
            int ci = wave * 8 + i;              // 32 chunks of 8 rows (A)
            int r  = ci * 8 + srow;
            const u8* ga = A + (size_t)(bm + r) * lda + k0 + sg;
            __builtin_amdgcn_global_load_lds(
                (const __attribute__((address_space(1))) void*)ga,
                (__attribute__((address_space(3))) void*)&As[ci * 1024], 16, 0, 0);
        }
#pragma unroll
        for (int i = 0; i < 4; ++i) {
            int ci = wave * 4 + i;              // 16 chunks of 8 rows (W)
            int r  = ci * 8 + srow;
            const u8* gw = Wq + (size_t)(bn + r) * K + k0 + sg;
            __builtin_amdgcn_global_load_lds(
                (const __attribute__((address_space(1))) void*)gw,
                (__attribute__((address_space(3))) void*)&Ws[ci * 1024], 16, 0, 0);
        }
        __syncthreads();

#pragma unroll
        for (int s = 0; s < 4; ++s) {
            const int c = s * 2 + half;         // logical 16B chunk 0..7
            intx4 af[4], bf[2];
#pragma unroll
            for (int i = 0; i < 4; ++i) {
                int r = wm + i * 32 + row32;
                af[i] = *(const intx4*)&As[r * 128 + ((c ^ (r & 7)) * 16)];
            }
#pragma unroll
            for (int j = 0; j < 2; ++j) {
                int r = wn + j * 32 + row32;
                bf[j] = *(const intx4*)&Ws[r * 128 + ((c ^ (r & 7)) * 16)];
            }
#pragma unroll
            for (int i = 0; i < 4; ++i)
#pragma unroll
                for (int j = 0; j < 2; ++j)
                    acc[i][j] = __builtin_amdgcn_mfma_i32_32x32x32_i8(
                        af[i], bf[j], acc[i][j], 0, 0, 0);
        }
        __syncthreads();
    }

    // epilogue: dequant. C/D layout col=lane&31, row=(r&3)+8*(r>>2)+4*half
    float sWv[2], Wsv[2], bv[2];
#pragma unroll
    for (int j = 0; j < 2; ++j) {
        int col = bn + wn + j * 32 + row32;
        sWv[j] = sW[col]; Wsv[j] = Wsum[col]; bv[j] = bias[col];
    }
#pragma unroll
    for (int i = 0; i < 4; ++i)
#pragma unroll
        for (int r = 0; r < 16; ++r) {
            int row = bm + wm + i * 32 + (r & 3) + 8 * (r >> 2) + 4 * half;
            float sa = sA[row * sstride], mu = muA[row * sstride];
#pragma unroll
            for (int j = 0; j < 2; ++j) {
                int col = bn + wn + j * 32 + row32;
                float v = (float)acc[i][j][r] * (sa * sWv[j]) + mu * Wsv[j] + bv[j];
                v = fmaxf(v, 0.f);
                C[(size_t)row * ldc + col] = f2b(v);
            }
        }
}

// ====== fused heads + physics/QP/softmax epilogue (bf16, unchanged) ========
__global__ __launch_bounds__(256, 2)
void k_heads_final(const u16* __restrict__ hbuf,       // bufB: h41 || h42
                   const u16* __restrict__ W51p, const float* __restrict__ b51p,
                   const u16* __restrict__ W52p, const float* __restrict__ b52p,
                   const float* __restrict__ x, const float* __restrict__ mean,
                   const float* __restrict__ std_,
                   const float* __restrict__ mean_label,
                   const float* __restrict__ std_label,
                   const float* __restrict__ wt, float* __restrict__ out) {
    __shared__ __align__(16) u16 As[128 * 64];     // 16 KB
    __shared__ __align__(16) u16 Ws[128 * 64];     // 16 KB
    __shared__ float x51s[128 * 20];               // 10 KB
    __shared__ float x52s[128 * 11];               // 5.5 KB

    const int tid  = threadIdx.x;
    const int wave = tid >> 6;
    const int lane = tid & 63;
    const int bm   = blockIdx.x * 128;

    const int srow = lane >> 3;
    const int sg   = ((lane & 7) ^ srow) * 8;

    const int wm    = (wave & 1) * 64;
    const int wn    = (wave >> 1) * 64;
    const int row32 = lane & 31;
    const int half  = lane >> 5;

    auto run_gemm = [&](const u16* Abase, const u16* Wp, const float* bp,
                        float* dst, int ncols) {
        floatx16 acc[2][2];
#pragma unroll
        for (int i = 0; i < 2; ++i)
#pragma unroll
            for (int j = 0; j < 2; ++j)
#pragma unroll
                for (int r = 0; r < 16; ++r) acc[i][j][r] = 0.f;

        for (int k0 = 0; k0 < 1024; k0 += 64) {
#pragma unroll
            for (int i = 0; i < 4; ++i) {
                int ci = wave * 4 + i;
                int r  = ci * 8 + srow;
                const u16* ga = Abase + (size_t)(bm + r) * 2048 + k0 + sg;
                __builtin_amdgcn_global_load_lds(
                    (const __attribute__((address_space(1))) void*)ga,
                    (__attribute__((address_space(3))) void*)&As[ci * 512], 16, 0, 0);
                const u16* gw = Wp + (size_t)r * 1024 + k0 + sg;
                __builtin_amdgcn_global_load_lds(
                    (const __attribute__((address_space(1))) void*)gw,
                    (__attribute__((address_space(3))) void*)&Ws[ci * 512], 16, 0, 0);
            }
            __syncthreads();
#pragma unroll
            for (int s = 0; s < 4; ++s) {
                const int c = s * 2 + half;
                short8 a0, a1, b0, b1;
                { int r = wm + row32;       a0 = *(const short8*)&As[r * 64 + ((c ^ (r & 7)) * 8)]; }
                { int r = wm + 32 + row32;  a1 = *(const short8*)&As[r * 64 + ((c ^ (r & 7)) * 8)]; }
                { int r = wn + row32;       b0 = *(const short8*)&Ws[r * 64 + ((c ^ (r & 7)) * 8)]; }
                { int r = wn + 32 + row32;  b1 = *(const short8*)&Ws[r * 64 + ((c ^ (r & 7)) * 8)]; }
                acc[0][0] = __builtin_amdgcn_mfma_f32_32x32x16_bf16(a0, b0, acc[0][0], 0, 0, 0);
                acc[0][1] = __builtin_amdgcn_mfma_f32_32x32x16_bf16(a0, b1, acc[0][1], 0, 0, 0);
                acc[1][0] = __builtin_amdgcn_mfma_f32_32x32x16_bf16(a1, b0, acc[1][0], 0, 0, 0);
                acc[1][1] = __builtin_amdgcn_mfma_f32_32x32x16_bf16(a1, b1, acc[1][1], 0, 0, 0);
            }
            __syncthreads();
        }
#pragma unroll
        for (int i = 0; i < 2; ++i)
#pragma unroll
            for (int j = 0; j < 2; ++j) {
                int col = wn + j * 32 + row32;
                if (col < ncols) {
                    float bj = bp[col];
#pragma unroll
                    for (int r = 0; r < 16; ++r) {
                        int row = wm + i * 32 + (r & 3) + 8 * (r >> 2) + 4 * half;
                        dst[row * ncols + col] = acc[i][j][r] + bj;
                    }
                }
            }
    };

    run_gemm(hbuf,        W51p, b51p, x51s, 20);
    run_gemm(hbuf + 1024, W52p, b52p, x52s, 11);
    __syncthreads();

    if (tid < 128) {
        int b = bm + tid;

        float w[10], m = -1e30f;
#pragma unroll
        for (int h = 0; h < 10; ++h) { w[h] = wt[h]; m = fmaxf(m, w[h]); }
        float ssum = 0.f;
#pragma unroll
        for (int h = 0; h < 10; ++h) { w[h] = __expf(w[h] - m); ssum += w[h]; }
        float winv = 1.f / ssum;

        float4 xv = ((const float4*)x)[b];
        float th1 = xv.x * std_[0] + mean[0];
        float w1v = xv.y * std_[1] + mean[1];
        float th2 = xv.z * std_[2] + mean[2];
        float w2v = xv.w * std_[3] + mean[3];
        float s1 = sinf(th1), c1 = cosf(th1);
        float s2 = sinf(th2), c2 = cosf(th2);
        float px = 3.f * c1 + 3.f * c2 - 0.f;
        float py = 3.f * s1 + 3.f * s2 - 7.f;
        float vx = -3.f * s1 * w1v - 3.f * s2 * w2v;
        float vy =  3.f * c1 * w1v + 3.f * c2 * w2v;
        float barrier = px * px + py * py - 16.f;
        float b_dot = 2.f * (px * vx + py * vy);
        float Lf2b = 2.f * vx * vx + 2.f * vy * vy
                   + 2.f * px * (-3.f * c1 * w1v * w1v - 3.f * c2 * w2v * w2v)
                   + 2.f * py * (-3.f * s1 * w1v * w1v - 3.f * s2 * w2v * w2v);
        float g1 = 2.f * px * (-3.f * s1) + 2.f * py * (3.f * c1);
        float g2 = 2.f * px * (-3.f * s2) + 2.f * py * (3.f * c2);
        float Gx = -g1, Gy = -g2;
        float Gdot = Gx * Gx + Gy * Gy;

        float alpha = 4.f / (1.f + expf(-x52s[tid * 11 + 0]));

        float rx = 0.f, ry = 0.f;
#pragma unroll
        for (int h = 0; h < 10; ++h) {
            float r0 = x51s[tid * 20 + 2 * h];
            float r1 = x51s[tid * 20 + 2 * h + 1];
            float beta = 4.f / (1.f + expf(-x52s[tid * 11 + 1 + h]));
            float hh = Lf2b + (alpha + beta) * b_dot + alpha * beta * barrier;
            float ux = -r0, uy = -r1;
            float viol = ux * Gx + uy * Gy - hh;
            float lam = fmaxf(viol / Gdot, 0.f);
            float sx = ux - lam * Gx;
            float sy = uy - lam * Gy;
            float wk = w[h] * winv;
            rx += wk * sx; ry += wk * sy;
        }
        out[2 * b]     = (rx - mean_label[0]) / std_label[0];
        out[2 * b + 1] = (ry - mean_label[1]) / std_label[1];
    }
}

extern "C" void kernel_launch(void* const* d_in, const int* in_sizes, int n_in,
                              void* d_out, int out_size, void* d_ws, size_t ws_size,
                              hipStream_t stream) {
    const float* x    = (const float*)d_in[0];
    const float* mean = (const float*)d_in[2];
    const float* std_ = (const float*)d_in[3];
    const float* mean_label = (const float*)d_in[4];
    const float* std_label  = (const float*)d_in[5];
    const float* W1  = (const float*)d_in[6];
    const float* b1  = (const float*)d_in[7];
    const float* W2  = (const float*)d_in[8];
    const float* b2  = (const float*)d_in[9];
    const float* W31 = (const float*)d_in[10];
    const float* b31 = (const float*)d_in[11];
    const float* W32 = (const float*)d_in[12];
    const float* b32 = (const float*)d_in[13];
    const float* W41 = (const float*)d_in[14];
    const float* b41 = (const float*)d_in[15];
    const float* W42 = (const float*)d_in[16];
    const float* b42 = (const float*)d_in[17];
    const float* W51 = (const float*)d_in[18];
    const float* b51 = (const float*)d_in[19];
    const float* W52 = (const float*)d_in[20];
    const float* b52 = (const float*)d_in[21];
    const float* wt  = (const float*)d_in[22];

    const int B = in_sizes[0] / 4;       // 16384

    char* wsp = (char*)d_ws;
    size_t off = 0;
    auto alloc = [&](size_t bytes) {
        void* p = wsp + off;
        off += (bytes + 255) & ~(size_t)255;
        return p;
    };
    u8*    W2q   = (u8*)   alloc((size_t)2048 * 2048);
    float* sW2   = (float*)alloc(2048 * 4);
    float* Wsum2 = (float*)alloc(2048 * 4);
    u8*    h1q   = (u8*)   alloc((size_t)B * 2048);
    float* sA1   = (float*)alloc((size_t)B * 4);
    float* muA1  = (float*)alloc((size_t)B * 4);
    u8*    W3q   = (u8*)   alloc((size_t)2048 * 2048);
    float* sW3   = (float*)alloc(2048 * 4);
    float* Wsum3 = (float*)alloc(2048 * 4);
    u8*    W41q  = (u8*)   alloc((size_t)1024 * 1024);
    float* sW41  = (float*)alloc(1024 * 4);
    float* Ws41  = (float*)alloc(1024 * 4);
    u8*    W42q  = (u8*)   alloc((size_t)1024 * 1024);
    float* sW42  = (float*)alloc(1024 * 4);
    float* Ws42  = (float*)alloc(1024 * 4);
    u16*   W51p  = (u16*)  alloc((size_t)128 * 1024 * 2);
    u16*   W52p  = (u16*)  alloc((size_t)128 * 1024 * 2);
    float* b51p  = (float*)alloc(512);
    float* b52p  = (float*)alloc(512);
    float* b3c   = (float*)alloc(2048 * 4);
    u8*    h2q   = (u8*)   alloc((size_t)B * 2048);
    float* s2a   = (float*)alloc((size_t)B * 4);
    float* mu2a  = (float*)alloc((size_t)B * 4);
    u8*    h34q  = (u8*)   alloc((size_t)B * 2048);
    float* s34   = (float*)alloc((size_t)2 * B * 4);
    float* mu34  = (float*)alloc((size_t)2 * B * 4);
    u16*   bufA  = (u16*)  alloc((size_t)B * 2048 * 2);   // h31||h32 (bf16)
    u16*   bufB  = (u16*)  alloc((size_t)B * 2048 * 2);   // h2 -> h41||h42 (bf16)
    const u8* NUL8 = nullptr;

    // stage-1 prep: W2 row-quant + layer-1-with-quant (gates L2)
    k_prep1<<<1536, 256, 0, stream>>>(W2, W2q, sW2, Wsum2,
                                      x, W1, b1, h1q, sA1, muA1);

    // L2 (i8): h2 = relu(deq(h1q @ W2q^T) + b2)  -> bufB (bf16)
    // grid: 16 x (64 + 81); backfill = 1296 slots for 1288 prep blocks
    k_gemmq<<<dim3(16, 64 + 81), 256, 0, stream>>>(
        h1q, W2q, sA1, muA1, sW2, Wsum2, b2, bufB, 2048, 2048, 2048, 1, 64,
        NUL8, NUL8, nullptr, nullptr, nullptr, nullptr, nullptr, nullptr, 0,
        W31, W32, W3q, sW3, Wsum3,
        W41, W41q, sW41, Ws41, W42, W42q, sW42, Ws42,
        W51, W51p, b51, b51p, W52, W52p, b52, b52p, b31, b32, b3c);

    // quantize h2 rows (B rows of 2048), NCH=4 compile-time
    k_aquant<4><<<B / 4, 256, 0, stream>>>(bufB, h2q, s2a, mu2a);

    // L3 (i8): h31||h32 = relu(deq(h2q @ W3q^T) + b3c) -> bufA (bf16)
    k_gemmq<<<dim3(16, 64), 256, 0, stream>>>(
        h2q, W3q, s2a, mu2a, sW3, Wsum3, b3c, bufA, 2048, 2048, 2048, 1, 64,
        NUL8, NUL8, nullptr, nullptr, nullptr, nullptr, nullptr, nullptr, 0,
        nullptr, nullptr, nullptr, nullptr, nullptr,
        nullptr, nullptr, nullptr, nullptr, nullptr, nullptr, nullptr, nullptr,
        nullptr, nullptr, nullptr, nullptr, nullptr, nullptr, nullptr, nullptr,
        nullptr, nullptr, nullptr);

    // quantize h31/h32 halves independently (2B rows of 1024), NCH=2
    k_aquant<2><<<2 * B / 4, 256, 0, stream>>>(bufA, h34q, s34, mu34);

    // L4 (i8, two GEMMs): h41 -> bufB[:, :1024]; h42 -> bufB[:, 1024:]
    k_gemmq<<<dim3(8, 128), 256, 0, stream>>>(
        h34q, W41q, s34, mu34, sW41, Ws41, b41, bufB,
        1024, 2048, 2048, 2, 128,
        h34q + 1024, W42q, s34 + 1, mu34 + 1, sW42, Ws42, b42, bufB + 1024, 64,
        nullptr, nullptr, nullptr, nullptr, nullptr,
        nullptr, nullptr, nullptr, nullptr, nullptr, nullptr, nullptr, nullptr,
        nullptr, nullptr, nullptr, nullptr, nullptr, nullptr, nullptr, nullptr,
        nullptr, nullptr, nullptr);

    // fused heads GEMMs + physics/QP/softmax epilogue (bf16)
    k_heads_final<<<B / 128, 256, 0, stream>>>(
        bufB, W51p, b51p, W52p, b52p, x, mean, std_,
        mean_label, std_label, wt, (float*)d_out);
}

// Round 12
// 402.944 us; speedup vs baseline: 1.6998x; 1.0166x over previous
//
#include <hip/hip_runtime.h>

typedef unsigned short u16;
typedef unsigned char  u8;
typedef unsigned int   u32;
typedef __attribute__((ext_vector_type(8)))  short short8;   // 8 bf16 (4 VGPRs)
typedef __attribute__((ext_vector_type(16))) float floatx16; // 32x32 MFMA C/D f32
typedef __attribute__((ext_vector_type(4)))  int   intx4;    // 16 i8 (4 VGPRs)
typedef __attribute__((ext_vector_type(16))) int   intx16;   // 32x32 i8 MFMA C/D
typedef __attribute__((ext_vector_type(8)))  u16   u16x8;
typedef __attribute__((ext_vector_type(4)))  u16   u16x4;

__device__ __forceinline__ u16 f2b(float f) {
    u32 u = __float_as_uint(f);
    u = (u + 0x7FFFu + ((u >> 16) & 1u)) >> 16;
    return (u16)u;
}
__device__ __forceinline__ float b2f(u16 h) {
    return __uint_as_float(((u32)h) << 16);
}
__device__ __forceinline__ int q8(float v, float inv) {
    return __float2int_rn(fminf(fmaxf(v * inv, -127.f), 127.f));
}

// ================= prep building blocks (256-thread granularity) ===========
__device__ __forceinline__ void pad_block(const float* __restrict__ Wsrc, int rows,
                                          u16* __restrict__ Wdst,
                                          const float* __restrict__ bsrc,
                                          float* __restrict__ bdst, int blk) {
    int i = blk * 256 + threadIdx.x;        // 32768 total (128x1024/4)
    int idx = i * 4;
    int r = idx >> 10;
    int c = idx & 1023;
    u16x4 o;
    if (r < rows) {
        float4 v = *(const float4*)&Wsrc[r * 1024 + c];
        o[0] = f2b(v.x); o[1] = f2b(v.y); o[2] = f2b(v.z); o[3] = f2b(v.w);
    } else {
        o[0] = 0; o[1] = 0; o[2] = 0; o[3] = 0;
    }
    *(u16x4*)&Wdst[idx] = o;
    if (i < 128) bdst[i] = (i < rows) ? bsrc[i] : 0.f;
}

// ---- W row-quant: one wave per row. q=rint(w/sw), sw=rowmax/127,
// ---- Wsum=sw*sum(q) for the asymmetric-A correction term.
__device__ __forceinline__ void wquant_row(const float* __restrict__ src,
                                           int K, u8* __restrict__ dstrow,
                                           float* __restrict__ sW,
                                           float* __restrict__ Wsum, int row_out) {
    const int lane = threadIdx.x & 63;
    const int iters = K >> 8;               // 256 floats/iter (64 lanes x float4)
    float mx = 0.f;
    for (int i = 0; i < iters; ++i) {
        float4 v = *(const float4*)&src[i * 256 + lane * 4];
        mx = fmaxf(mx, fmaxf(fmaxf(fabsf(v.x), fabsf(v.y)),
                             fmaxf(fabsf(v.z), fabsf(v.w))));
    }
#pragma unroll
    for (int off = 32; off >= 1; off >>= 1) mx = fmaxf(mx, __shfl_xor(mx, off));
    float sw  = fmaxf(mx * (1.f / 127.f), 1e-20f);
    float inv = 1.f / sw;
    int ssum = 0;
    for (int i = 0; i < iters; ++i) {
        float4 v = *(const float4*)&src[i * 256 + lane * 4];
        int q0 = q8(v.x, inv), q1 = q8(v.y, inv), q2 = q8(v.z, inv), q3 = q8(v.w, inv);
        ssum += q0 + q1 + q2 + q3;
        u32 p = (q0 & 255) | ((q1 & 255) << 8) | ((q2 & 255) << 16) | ((q3 & 255) << 24);
        *(u32*)&dstrow[i * 256 + lane * 4] = p;
    }
#pragma unroll
    for (int off = 32; off >= 1; off >>= 1) ssum += __shfl_xor(ssum, off);
    if (lane == 0) { sW[row_out] = sw; Wsum[row_out] = sw * (float)ssum; }
}

// ---- layer 1 + per-row asymmetric i8 quant of h1 ----
__device__ __forceinline__ void l1q_block(const float* __restrict__ x,
                                          const float* __restrict__ W1,
                                          const float* __restrict__ b1,
                                          u8* __restrict__ h1q,
                                          float* __restrict__ sA,
                                          float* __restrict__ muA, int blk) {
    __shared__ float wmx[4], wmn[4];
    const int t    = threadIdx.x;
    const int wave = t >> 6;
    const int lane = t & 63;
    const int b0 = blk * 16;
    const int n0 = t * 8;
    float4 wreg[8]; float breg[8];
    const float4* W14 = (const float4*)W1;
#pragma unroll
    for (int i = 0; i < 8; ++i) { wreg[i] = W14[n0 + i]; breg[i] = b1[n0 + i]; }
    for (int r = 0; r < 16; ++r) {
        int b = b0 + r;
        float4 xv = ((const float4*)x)[b];
        float v[8];
        float lmx = 0.f, lmn = 3.4e38f;
#pragma unroll
        for (int i = 0; i < 8; ++i) {
            float s = xv.x * wreg[i].x + xv.y * wreg[i].y +
                      xv.z * wreg[i].z + xv.w * wreg[i].w + breg[i];
            s = fmaxf(s, 0.f);
            v[i] = s;
            lmx = fmaxf(lmx, s); lmn = fminf(lmn, s);
        }
#pragma unroll
        for (int off = 32; off >= 1; off >>= 1) {
            lmx = fmaxf(lmx, __shfl_xor(lmx, off));
            lmn = fminf(lmn, __shfl_xor(lmn, off));
        }
        if (lane == 0) { wmx[wave] = lmx; wmn[wave] = lmn; }
        __syncthreads();
        float mx = fmaxf(fmaxf(wmx[0], wmx[1]), fmaxf(wmx[2], wmx[3]));
        float mn = fminf(fminf(wmn[0], wmn[1]), fminf(wmn[2], wmn[3]));
        float mu  = 0.5f * (mx + mn);
        float s   = fmaxf((mx - mn) * (1.f / 254.f), 1e-20f);
        float inv = 1.f / s;
        int q[8];
#pragma unroll
        for (int i = 0; i < 8; ++i) q[i] = q8(v[i] - mu, inv);
        uint2 p;
        p.x = (q[0] & 255) | ((q[1] & 255) << 8) | ((q[2] & 255) << 16) | ((q[3] & 255) << 24);
        p.y = (q[4] & 255) | ((q[5] & 255) << 8) | ((q[6] & 255) << 16) | ((q[7] & 255) << 24);
        *(uint2*)&h1q[(size_t)b * 2048 + n0] = p;
        if (t == 0) { sA[b] = s; muA[b] = mu; }
        __syncthreads();
    }
}

// ===== stage-1 prep: ALL weight prep + layer 1 (2824 blocks) ===============
// [0,512) W2q | [512,1536) l1q | [1536,2048) W3q | [2048,2304) W41q |
// [2304,2560) W42q | [2560,2688) W51p | [2688,2816) W52p | [2816,2824) b3c
__global__ __launch_bounds__(256)
void k_prep1(const float* W2, u8* W2q, float* sW2, float* Wsum2,
             const float* x, const float* W1, const float* b1,
             u8* h1q, float* sA1, float* muA1,
             const float* W31, const float* W32, u8* W3q, float* sW3, float* Wsum3,
             const float* W41, u8* W41q, float* sW41, float* Ws41,
             const float* W42, u8* W42q, float* sW42, float* Ws42,
             const float* W51, u16* W51p, const float* b51, float* b51p,
             const float* W52, u16* W52p, const float* b52, float* b52p,
             const float* b31, const float* b32, float* b3c) {
    int blk = blockIdx.x;
    if (blk < 512) {
        int row = blk * 4 + (threadIdx.x >> 6);
        wquant_row(W2 + (size_t)row * 2048, 2048, W2q + (size_t)row * 2048,
                   sW2, Wsum2, row);
        return;
    }
    blk -= 512;
    if (blk < 1024) { l1q_block(x, W1, b1, h1q, sA1, muA1, blk); return; }
    blk -= 1024;
    if (blk < 512) {
        int row = blk * 4 + (threadIdx.x >> 6);
        const float* src = (row < 1024) ? W31 + (size_t)row * 2048
                                        : W32 + (size_t)(row - 1024) * 2048;
        wquant_row(src, 2048, W3q + (size_t)row * 2048, sW3, Wsum3, row);
        return;
    }
    blk -= 512;
    if (blk < 256) {
        int row = blk * 4 + (threadIdx.x >> 6);
        wquant_row(W41 + (size_t)row * 1024, 1024, W41q + (size_t)row * 1024,
                   sW41, Ws41, row);
        return;
    }
    blk -= 256;
    if (blk < 256) {
        int row = blk * 4 + (threadIdx.x >> 6);
        wquant_row(W42 + (size_t)row * 1024, 1024, W42q + (size_t)row * 1024,
                   sW42, Ws42, row);
        return;
    }
    blk -= 256;
    if (blk < 128) { pad_block(W51, 20, W51p, b51, b51p, blk); return; }
    blk -= 128;
    if (blk < 128) { pad_block(W52, 11, W52p, b52, b52p, blk); return; }
    blk -= 128;
    if (blk < 8) {
        int i = blk * 256 + threadIdx.x;
        b3c[i] = (i < 1024) ? b31[i] : b32[i - 1024];
    }
}

// ===== activation row-quant: one wave per row (asymmetric, centered) =======
// NCH compile-time -> vbuf fully in VGPRs (runtime bound spilled: R10 169us).
template<int NCH>
__global__ __launch_bounds__(256)
void k_aquant(const u16* __restrict__ src, u8* __restrict__ dst,
              float* __restrict__ s, float* __restrict__ mu) {
    const int wave = threadIdx.x >> 6;
    const int lane = threadIdx.x & 63;
    const int row  = blockIdx.x * 4 + wave;
    const int rowlen = NCH * 512;
    const u16* sr = src + (size_t)row * rowlen;
    u8*       dr  = dst + (size_t)row * rowlen;
    u16x8 vbuf[NCH];
    float mx = -3.4e38f, mn = 3.4e38f;
#pragma unroll
    for (int c = 0; c < NCH; ++c) {
        u16x8 v = *(const u16x8*)&sr[c * 512 + lane * 8];
        vbuf[c] = v;
#pragma unroll
        for (int i = 0; i < 8; ++i) {
            float f = b2f(v[i]);
            mx = fmaxf(mx, f); mn = fminf(mn, f);
        }
    }
#pragma unroll
    for (int off = 32; off >= 1; off >>= 1) {
        mx = fmaxf(mx, __shfl_xor(mx, off));
        mn = fminf(mn, __shfl_xor(mn, off));
    }
    float m  = 0.5f * (mx + mn);
    float sc = fmaxf((mx - mn) * (1.f / 254.f), 1e-20f);
    float inv = 1.f / sc;
#pragma unroll
    for (int c = 0; c < NCH; ++c) {
        u16x8 v = vbuf[c];
        int q[8];
#pragma unroll
        for (int i = 0; i < 8; ++i) q[i] = q8(b2f(v[i]) - m, inv);
        uint2 p;
        p.x = (q[0] & 255) | ((q[1] & 255) << 8) | ((q[2] & 255) << 16) | ((q[3] & 255) << 24);
        p.y = (q[4] & 255) | ((q[5] & 255) << 8) | ((q[6] & 255) << 16) | ((q[7] & 255) << 24);
        *(uint2*)&dr[c * 512 + lane * 8] = p;
    }
    if (lane == 0) { s[row] = sc; mu[row] = m; }
}

// ================= i8 MFMA GEMM: 256x128 tile, BK=128 i8 (pure) ============
// C = relu(deq(Aq @ Wq^T) + b). A per-row asymmetric (mu,s; scale index =
// row*sstride), W per-row symmetric (sW, Wsum). Verified i8 fragment layout
// (R9). Optional second GEMM for swizzled by >= split.
__global__ __launch_bounds__(256, 2)
void k_gemmq(const u8* __restrict__ A, const u8* __restrict__ Wq,
             const float* __restrict__ sA, const float* __restrict__ muA,
             const float* __restrict__ sW, const float* __restrict__ Wsum,
             const float* __restrict__ bias, u16* __restrict__ C,
             int K, int lda, int ldc, int sstride,
             const u8* A2, const u8* Wq2,
             const float* sA2, const float* muA2,
             const float* sW2, const float* Wsum2,
             const float* bias2, u16* C2, int split) {
    __shared__ __align__(16) u8 As[256 * 128];  // 32 KB
    __shared__ __align__(16) u8 Ws[128 * 128];  // 16 KB

    const int tid  = threadIdx.x;
    const int wave = tid >> 6;
    const int lane = tid & 63;

    int flat = blockIdx.y * gridDim.x + blockIdx.x;
    int xcd = flat & 7;
    int p   = flat >> 3;
    int bx  = p % gridDim.x;
    int by  = (p / gridDim.x) * 8 + xcd;
    if (A2 != nullptr && by >= split) {
        A = A2; Wq = Wq2; sA = sA2; muA = muA2; sW = sW2; Wsum = Wsum2;
        bias = bias2; C = C2; by -= split;
    }
    const int bm = by * 256;
    const int bn = bx * 128;

    const int srow = lane >> 3;                     // 0..7
    const int sg   = ((lane & 7) ^ srow) * 16;      // swizzled global byte offset

    const int wm    = (wave & 1) * 128;
    const int wn    = (wave >> 1) * 64;
    const int row32 = lane & 31;
    const int half  = lane >> 5;

    intx16 acc[4][2];
#pragma unroll
    for (int i = 0; i < 4; ++i)
#pragma unroll
        for (int j = 0; j < 2; ++j)
#pragma unroll
            for (int r = 0; r < 16; ++r) acc[i][j][r] = 0;

    for (int k0 = 0; k0 < K; k0 += 128) {
#pragma unroll
        for (int i = 0; i < 8; ++i) {
            int ci = wave * 8 + i;              // 32 chunks of 8 rows (A)
            int r  = ci * 8 + srow;
            const u8* ga = A + (size_t)(bm + r) * lda + k0 + sg;
            __builtin_amdgcn_global_load_lds(
                (const __attribute__((address_space(1))) void*)ga,
                (__attribute__((address_space(3))) void*)&As[ci * 1024], 16, 0, 0);
        }
#pragma unroll
        for (int i = 0; i < 4; ++i) {
            int ci = wave * 4 + i;              // 16 chunks of 8 rows (W)
            int r  = ci * 8 + srow;
            const u8* gw = Wq + (size_t)(bn + r) * K + k0 + sg;
            __builtin_amdgcn_global_load_lds(
                (const __attribute__((address_space(1))) void*)gw,
                (__attribute__((address_space(3))) void*)&Ws[ci * 1024], 16, 0, 0);
        }
        __syncthreads();

#pragma unroll
        for (int s = 0; s < 4; ++s) {
            const int c = s * 2 + half;         // logical 16B chunk 0..7
            intx4 af[4], bf[2];
#pragma unroll
            for (int i = 0; i < 4; ++i) {
                int r = wm + i * 32 + row32;
                af[i] = *(const intx4*)&As[r * 128 + ((c ^ (r & 7)) * 16)];
            }
#pragma unroll
            for (int j = 0; j < 2; ++j) {
                int r = wn + j * 32 + row32;
                bf[j] = *(const intx4*)&Ws[r * 128 + ((c ^ (r & 7)) * 16)];
            }
#pragma unroll
            for (int i = 0; i < 4; ++i)
#pragma unroll
                for (int j = 0; j < 2; ++j)
                    acc[i][j] = __builtin_amdgcn_mfma_i32_32x32x32_i8(
                        af[i], bf[j], acc[i][j], 0, 0, 0);
        }
        __syncthreads();
    }

    // epilogue: dequant. C/D layout col=lane&31, row=(r&3)+8*(r>>2)+4*half
    float sWv[2], Wsv[2], bv[2];
#pragma unroll
    for (int j = 0; j < 2; ++j) {
        int col = bn + wn + j * 32 + row32;
        sWv[j] = sW[col]; Wsv[j] = Wsum[col]; bv[j] = bias[col];
    }
#pragma unroll
    for (int i = 0; i < 4; ++i)
#pragma unroll
        for (int r = 0; r < 16; ++r) {
            int row = bm + wm + i * 32 + (r & 3) + 8 * (r >> 2) + 4 * half;
            float sa = sA[row * sstride], mu = muA[row * sstride];
#pragma unroll
            for (int j = 0; j < 2; ++j) {
                int col = bn + wn + j * 32 + row32;
                float v = (float)acc[i][j][r] * (sa * sWv[j]) + mu * Wsv[j] + bv[j];
                v = fmaxf(v, 0.f);
                C[(size_t)row * ldc + col] = f2b(v);
            }
        }
}

// ====== fused heads + physics/QP/softmax epilogue, N=32 ====================
// 128 blocks x 256 threads; block owns 128 batch rows. 4 waves:
// g=wave>>1 selects GEMM (0: x51 from h41, 1: x52 from h42), wave&1 selects
// the 64-row half. Wave tile 64x32 (2x1 of mfma_f32_32x32x16_bf16, 32 acc
// regs). W read per block: 2 x 32x1024 bf16 (vs 128-wide before: 4x less
// compute, 4x less W traffic). Outputs land in LDS fp32; per-row QP follows.
__global__ __launch_bounds__(256, 2)
void k_heads_final(const u16* __restrict__ hbuf,       // bufB: h41 || h42
                   const u16* __restrict__ W51p, const float* __restrict__ b51p,
                   const u16* __restrict__ W52p, const float* __restrict__ b52p,
                   const float* __restrict__ x, const float* __restrict__ mean,
                   const float* __restrict__ std_,
                   const float* __restrict__ mean_label,
                   const float* __restrict__ std_label,
                   const float* __restrict__ wt, float* __restrict__ out) {
    __shared__ __align__(16) u16 A1[128 * 64];     // 16 KB (h41 tile)
    __shared__ __align__(16) u16 A2[128 * 64];     // 16 KB (h42 tile)
    __shared__ __align__(16) u16 Wl[2][32 * 64];   // 4 KB each
    __shared__ float x51s[128 * 20];               // 10 KB
    __shared__ float x52s[128 * 11];               // 5.5 KB

    const int tid  = threadIdx.x;
    const int wave = tid >> 6;
    const int lane = tid & 63;
    const int bm   = blockIdx.x * 128;

    const int srow = lane >> 3;
    const int sg   = ((lane & 7) ^ srow) * 8;

    const int g     = wave >> 1;        // 0: x51, 1: x52
    const int wm    = (wave & 1) * 64;  // row half within the 128-row block
    const int row32 = lane & 31;
    const int half  = lane >> 5;

    const u16* Abase = hbuf + (g ? 1024 : 0);
    const u16* Wp    = g ? W52p : W51p;
    u16* Asl = g ? A2 : A1;

    floatx16 acc[2];
#pragma unroll
    for (int i = 0; i < 2; ++i)
#pragma unroll
        for (int r = 0; r < 16; ++r) acc[i][r] = 0.f;

    for (int k0 = 0; k0 < 1024; k0 += 64) {
        // stage own 64 A rows (8 issues) + W tile (4 issues, even waves)
#pragma unroll
        for (int i = 0; i < 8; ++i) {
            int rl = wm + i * 8 + srow;
            const u16* ga = Abase + (size_t)(bm + rl) * 2048 + k0 + sg;
            __builtin_amdgcn_global_load_lds(
                (const __attribute__((address_space(1))) void*)ga,
                (__attribute__((address_space(3))) void*)&Asl[(wm + i * 8) * 64],
                16, 0, 0);
        }
        if ((wave & 1) == 0) {
#pragma unroll
            for (int i = 0; i < 4; ++i) {
                int r = i * 8 + srow;
                const u16* gw = Wp + (size_t)r * 1024 + k0 + sg;
                __builtin_amdgcn_global_load_lds(
                    (const __attribute__((address_space(1))) void*)gw,
                    (__attribute__((address_space(3))) void*)&Wl[g][(i * 8) * 64],
                    16, 0, 0);
            }
        }
        __syncthreads();
#pragma unroll
        for (int s = 0; s < 4; ++s) {
            const int c = s * 2 + half;
            short8 a0, a1, bf;
            { int r = wm + row32;       a0 = *(const short8*)&Asl[r * 64 + ((c ^ (r & 7)) * 8)]; }
            { int r = wm + 32 + row32;  a1 = *(const short8*)&Asl[r * 64 + ((c ^ (r & 7)) * 8)]; }
            { int r = row32;            bf = *(const short8*)&Wl[g][r * 64 + ((c ^ (r & 7)) * 8)]; }
            acc[0] = __builtin_amdgcn_mfma_f32_32x32x16_bf16(a0, bf, acc[0], 0, 0, 0);
            acc[1] = __builtin_amdgcn_mfma_f32_32x32x16_bf16(a1, bf, acc[1], 0, 0, 0);
        }
        __syncthreads();
    }

    // write needed cols to LDS fp32 (+bias). col=row32, row per C/D layout.
    {
        int col = row32;
        int ncols = g ? 11 : 20;
        if (col < ncols) {
            float bj = (g ? b52p : b51p)[col];
            float* dst = g ? x52s : x51s;
#pragma unroll
            for (int i = 0; i < 2; ++i)
#pragma unroll
                for (int r = 0; r < 16; ++r) {
                    int row = wm + i * 32 + (r & 3) + 8 * (r >> 2) + 4 * half;
                    dst[row * ncols + col] = acc[i][r] + bj;
                }
        }
    }
    __syncthreads();

    if (tid < 128) {
        int b = bm + tid;

        float w[10], m = -1e30f;
#pragma unroll
        for (int h = 0; h < 10; ++h) { w[h] = wt[h]; m = fmaxf(m, w[h]); }
        float ssum = 0.f;
#pragma unroll
        for (int h = 0; h < 10; ++h) { w[h] = __expf(w[h] - m); ssum += w[h]; }
        float winv = 1.f / ssum;

        float4 xv = ((const float4*)x)[b];
        float th1 = xv.x * std_[0] + mean[0];
        float w1v = xv.y * std_[1] + mean[1];
        float th2 = xv.z * std_[2] + mean[2];
        float w2v = xv.w * std_[3] + mean[3];
        float s1 = sinf(th1), c1 = cosf(th1);
        float s2 = sinf(th2), c2 = cosf(th2);
        float px = 3.f * c1 + 3.f * c2 - 0.f;
        float py = 3.f * s1 + 3.f * s2 - 7.f;
        float vx = -3.f * s1 * w1v - 3.f * s2 * w2v;
        float vy =  3.f * c1 * w1v + 3.f * c2 * w2v;
        float barrier = px * px + py * py - 16.f;
        float b_dot = 2.f * (px * vx + py * vy);
        float Lf2b = 2.f * vx * vx + 2.f * vy * vy
                   + 2.f * px * (-3.f * c1 * w1v * w1v - 3.f * c2 * w2v * w2v)
                   + 2.f * py * (-3.f * s1 * w1v * w1v - 3.f * s2 * w2v * w2v);
        float g1 = 2.f * px * (-3.f * s1) + 2.f * py * (3.f * c1);
        float g2 = 2.f * px * (-3.f * s2) + 2.f * py * (3.f * c2);
        float Gx = -g1, Gy = -g2;
        float Gdot = Gx * Gx + Gy * Gy;

        float alpha = 4.f / (1.f + expf(-x52s[tid * 11 + 0]));

        float rx = 0.f, ry = 0.f;
#pragma unroll
        for (int h = 0; h < 10; ++h) {
            float r0 = x51s[tid * 20 + 2 * h];
            float r1 = x51s[tid * 20 + 2 * h + 1];
            float beta = 4.f / (1.f + expf(-x52s[tid * 11 + 1 + h]));
            float hh = Lf2b + (alpha + beta) * b_dot + alpha * beta * barrier;
            float ux = -r0, uy = -r1;
            float viol = ux * Gx + uy * Gy - hh;
            float lam = fmaxf(viol / Gdot, 0.f);
            float sx = ux - lam * Gx;
            float sy = uy - lam * Gy;
            float wk = w[h] * winv;
            rx += wk * sx; ry += wk * sy;
        }
        out[2 * b]     = (rx - mean_label[0]) / std_label[0];
        out[2 * b + 1] = (ry - mean_label[1]) / std_label[1];
    }
}

extern "C" void kernel_launch(void* const* d_in, const int* in_sizes, int n_in,
                              void* d_out, int out_size, void* d_ws, size_t ws_size,
                              hipStream_t stream) {
    const float* x    = (const float*)d_in[0];
    const float* mean = (const float*)d_in[2];
    const float* std_ = (const float*)d_in[3];
    const float* mean_label = (const float*)d_in[4];
    const float* std_label  = (const float*)d_in[5];
    const float* W1  = (const float*)d_in[6];
    const float* b1  = (const float*)d_in[7];
    const float* W2  = (const float*)d_in[8];
    const float* b2  = (const float*)d_in[9];
    const float* W31 = (const float*)d_in[10];
    const float* b31 = (const float*)d_in[11];
    const float* W32 = (const float*)d_in[12];
    const float* b32 = (const float*)d_in[13];
    const float* W41 = (const float*)d_in[14];
    const float* b41 = (const float*)d_in[15];
    const float* W42 = (const float*)d_in[16];
    const float* b42 = (const float*)d_in[17];
    const float* W51 = (const float*)d_in[18];
    const float* b51 = (const float*)d_in[19];
    const float* W52 = (const float*)d_in[20];
    const float* b52 = (const float*)d_in[21];
    const float* wt  = (const float*)d_in[22];

    const int B = in_sizes[0] / 4;       // 16384

    char* wsp = (char*)d_ws;
    size_t off = 0;
    auto alloc = [&](size_t bytes) {
        void* p = wsp + off;
        off += (bytes + 255) & ~(size_t)255;
        return p;
    };
    u8*    W2q   = (u8*)   alloc((size_t)2048 * 2048);
    float* sW2   = (float*)alloc(2048 * 4);
    float* Wsum2 = (float*)alloc(2048 * 4);
    u8*    h1q   = (u8*)   alloc((size_t)B * 2048);
    float* sA1   = (float*)alloc((size_t)B * 4);
    float* muA1  = (float*)alloc((size_t)B * 4);
    u8*    W3q   = (u8*)   alloc((size_t)2048 * 2048);
    float* sW3   = (float*)alloc(2048 * 4);
    float* Wsum3 = (float*)alloc(2048 * 4);
    u8*    W41q  = (u8*)   alloc((size_t)1024 * 1024);
    float* sW41  = (float*)alloc(1024 * 4);
    float* Ws41  = (float*)alloc(1024 * 4);
    u8*    W42q  = (u8*)   alloc((size_t)1024 * 1024);
    float* sW42  = (float*)alloc(1024 * 4);
    float* Ws42  = (float*)alloc(1024 * 4);
    u16*   W51p  = (u16*)  alloc((size_t)128 * 1024 * 2);
    u16*   W52p  = (u16*)  alloc((size_t)128 * 1024 * 2);
    float* b51p  = (float*)alloc(512);
    float* b52p  = (float*)alloc(512);
    float* b3c   = (float*)alloc(2048 * 4);
    u8*    h2q   = (u8*)   alloc((size_t)B * 2048);
    float* s2a   = (float*)alloc((size_t)B * 4);
    float* mu2a  = (float*)alloc((size_t)B * 4);
    u8*    h34q  = (u8*)   alloc((size_t)B * 2048);
    float* s34   = (float*)alloc((size_t)2 * B * 4);
    float* mu34  = (float*)alloc((size_t)2 * B * 4);
    u16*   bufA  = (u16*)  alloc((size_t)B * 2048 * 2);   // h31||h32 (bf16)
    u16*   bufB  = (u16*)  alloc((size_t)B * 2048 * 2);   // h2 -> h41||h42 (bf16)
    const u8* NUL8 = nullptr;

    // stage-1 prep: ALL weight quant/pack + layer-1-with-quant (2824 blocks)
    k_prep1<<<2824, 256, 0, stream>>>(
        W2, W2q, sW2, Wsum2, x, W1, b1, h1q, sA1, muA1,
        W31, W32, W3q, sW3, Wsum3,
        W41, W41q, sW41, Ws41, W42, W42q, sW42, Ws42,
        W51, W51p, b51, b51p, W52, W52p, b52, b52p, b31, b32, b3c);

    // L2 (i8, pure): h2 = relu(deq(h1q @ W2q^T) + b2)  -> bufB (bf16)
    k_gemmq<<<dim3(16, 64), 256, 0, stream>>>(
        h1q, W2q, sA1, muA1, sW2, Wsum2, b2, bufB, 2048, 2048, 2048, 1,
        NUL8, NUL8, nullptr, nullptr, nullptr, nullptr, nullptr, nullptr, 0);

    // quantize h2 rows (B rows of 2048), NCH=4
    k_aquant<4><<<B / 4, 256, 0, stream>>>(bufB, h2q, s2a, mu2a);

    // L3 (i8): h31||h32 = relu(deq(h2q @ W3q^T) + b3c) -> bufA (bf16)
    k_gemmq<<<dim3(16, 64), 256, 0, stream>>>(
        h2q, W3q, s2a, mu2a, sW3, Wsum3, b3c, bufA, 2048, 2048, 2048, 1,
        NUL8, NUL8, nullptr, nullptr, nullptr, nullptr, nullptr, nullptr, 0);

    // quantize h31/h32 halves independently (2B rows of 1024), NCH=2
    k_aquant<2><<<2 * B / 4, 256, 0, stream>>>(bufA, h34q, s34, mu34);

    // L4 (i8, two GEMMs): h41 -> bufB[:, :1024]; h42 -> bufB[:, 1024:]
    k_gemmq<<<dim3(8, 128), 256, 0, stream>>>(
        h34q, W41q, s34, mu34, sW41, Ws41, b41, bufB,
        1024, 2048, 2048, 2,
        h34q + 1024, W42q, s34 + 1, mu34 + 1, sW42, Ws42, b42, bufB + 1024, 64);

    // fused heads GEMMs (N=32) + physics/QP/softmax epilogue (bf16)
    k_heads_final<<<B / 128, 256, 0, stream>>>(
        bufB, W51p, b51p, W52p, b52p, x, mean, std_,
        mean_label, std_label, wt, (float*)d_out);
}